// Round 1
// baseline (5654.628 us; speedup 1.0000x reference)
//
#include <hip/hip_runtime.h>

// DiffeqSolver: 49 RK4(3/8) steps of y' = W2 @ tanh(W1 @ y + b1) + b2
// rows = 3*2048 = 6144 independent ODEs, dim 128 (123 latents + 5 aug zeros)
// Output: (3, 2048, 50, 128) fp32, includes y0 at t=0.
//
// Baseline fp32 design (round 1):
//   256 blocks x 256 threads, 24 rows/block, all 49 steps inside one kernel
//   (rows independent -> no inter-block communication).
//   Thread (rowg=tid>>5, colg=tid&31) owns 3 rows x 4 dims of state in regs
//   (dims strided: d = colg + 32*j  -> coalesced stores, conflict-free LDS).
//   Per f-eval: y_eval -> LDS, phase A GEMM (24x256 += 24x128 @ 128x256) with
//   W1 staged in LDS k-chunks of 64 (stride 68 words: 16B-aligned, 8-slot
//   spread), tanh -> LDS, phase B GEMM (24x128) with W2 staged in hh-chunks
//   of 128 (stride 132 words).

#define NBLK 256
#define RPB  24

__global__ __launch_bounds__(256, 1)
void ode_rk4_kernel(const float* __restrict__ fp,      // (3,2048,123)
                    const float* __restrict__ tsteps,  // (50)
                    const float* __restrict__ W1,      // (256,128) row-major
                    const float* __restrict__ b1,      // (256)
                    const float* __restrict__ W2,      // (128,256) row-major
                    const float* __restrict__ b2,      // (128)
                    float* __restrict__ out)           // (3,2048,50,128)
{
    __shared__ __align__(16) float ys_[RPB * 128];   // eval-point y, 12 KB
    __shared__ __align__(16) float hs_[RPB * 256];   // hidden acts,  24 KB
    __shared__ __align__(16) float ws_[17408];       // weight chunk, 68 KB
    __shared__ float bs1[256];
    __shared__ float bs2[128];

    const int tid  = threadIdx.x;
    const int rowg = tid >> 5;   // 0..7  -> rows rowg*3 .. rowg*3+2
    const int colg = tid & 31;   // 0..31 -> dims  colg + 32*j
    const int blk  = blockIdx.x;

    bs1[tid] = b1[tid];
    if (tid < 128) bs2[tid] = b2[tid];

    // ---- initial state + t=0 output ----
    float y[3][4], k1[3][4], k2[3][4], k3[3][4], ke[3][4];
#pragma unroll
    for (int i = 0; i < 3; ++i) {
        const int gr = blk * RPB + rowg * 3 + i;   // global row
#pragma unroll
        for (int j = 0; j < 4; ++j) {
            const int d = colg + 32 * j;
            float v = (d < 123) ? fp[gr * 123 + d] : 0.f;
            y[i][j] = v;
            out[(gr * 50 + 0) * 128 + d] = v;
        }
    }

    for (int s = 0; s < 49; ++s) {
        const float h = tsteps[s + 1] - tsteps[s];

#pragma unroll 1
        for (int e = 0; e < 4; ++e) {
            // ---- build eval point, publish to LDS ----
#pragma unroll
            for (int i = 0; i < 3; ++i) {
                const int lr = rowg * 3 + i;
#pragma unroll
                for (int j = 0; j < 4; ++j) {
                    float v;
                    if (e == 0)      v = y[i][j];
                    else if (e == 1) v = y[i][j] + (h * (1.f / 3.f)) * k1[i][j];
                    else if (e == 2) v = y[i][j] + h * (k2[i][j] - (1.f / 3.f) * k1[i][j]);
                    else             v = y[i][j] + h * (k1[i][j] - k2[i][j] + k3[i][j]);
                    ys_[lr * 128 + colg + 32 * j] = v;
                }
            }

            // ---- phase A: acc[3][8] = ys @ W1^T + b1 (cols strided) ----
            float acc[3][8];
#pragma unroll
            for (int i = 0; i < 3; ++i)
#pragma unroll
                for (int jj = 0; jj < 8; ++jj)
                    acc[i][jj] = bs1[colg + 32 * jj];

            for (int kc = 0; kc < 128; kc += 64) {
                __syncthreads();   // covers ys_ publish + prior ws_ readers
#pragma unroll
                for (int p = 0; p < 16; ++p) {
                    const int idx = p * 256 + tid;       // 0..4095 float4s
                    const int c  = idx >> 4;             // 0..255
                    const int k4 = idx & 15;             // 0..15
                    *(float4*)&ws_[c * 68 + k4 * 4] =
                        *(const float4*)(W1 + c * 128 + kc + k4 * 4);
                }
                __syncthreads();
#pragma unroll 2
                for (int k4 = 0; k4 < 16; ++k4) {
                    float4 yv[3];
#pragma unroll
                    for (int i = 0; i < 3; ++i)
                        yv[i] = *(const float4*)&ys_[(rowg * 3 + i) * 128 + kc + k4 * 4];
#pragma unroll
                    for (int jj = 0; jj < 8; ++jj) {
                        const float4 wv = *(const float4*)&ws_[(colg + 32 * jj) * 68 + k4 * 4];
#pragma unroll
                        for (int i = 0; i < 3; ++i)
                            acc[i][jj] += yv[i].x * wv.x + yv[i].y * wv.y
                                        + yv[i].z * wv.z + yv[i].w * wv.w;
                    }
                }
            }

            // ---- tanh -> hs_ ----
#pragma unroll
            for (int i = 0; i < 3; ++i) {
                const int lr = rowg * 3 + i;
#pragma unroll
                for (int jj = 0; jj < 8; ++jj)
                    hs_[lr * 256 + colg + 32 * jj] = tanhf(acc[i][jj]);
            }

            // ---- phase B: accB[3][4] = hs @ W2^T + b2 ----
            float accB[3][4];
#pragma unroll
            for (int i = 0; i < 3; ++i)
#pragma unroll
                for (int jd = 0; jd < 4; ++jd)
                    accB[i][jd] = bs2[colg + 32 * jd];

            for (int hc = 0; hc < 256; hc += 128) {
                __syncthreads();   // covers hs_ publish + phase-A ws_ readers
#pragma unroll
                for (int p = 0; p < 16; ++p) {
                    const int idx = p * 256 + tid;       // 0..4095 float4s
                    const int dd = idx >> 5;             // 0..127
                    const int h4 = idx & 31;             // 0..31
                    *(float4*)&ws_[dd * 132 + h4 * 4] =
                        *(const float4*)(W2 + dd * 256 + hc + h4 * 4);
                }
                __syncthreads();
#pragma unroll 2
                for (int h4 = 0; h4 < 32; ++h4) {
                    float4 hv[3];
#pragma unroll
                    for (int i = 0; i < 3; ++i)
                        hv[i] = *(const float4*)&hs_[(rowg * 3 + i) * 256 + hc + h4 * 4];
#pragma unroll
                    for (int jd = 0; jd < 4; ++jd) {
                        const float4 wv = *(const float4*)&ws_[(colg + 32 * jd) * 132 + h4 * 4];
#pragma unroll
                        for (int i = 0; i < 3; ++i)
                            accB[i][jd] += hv[i].x * wv.x + hv[i].y * wv.y
                                         + hv[i].z * wv.z + hv[i].w * wv.w;
                    }
                }
            }

            // ---- stash eval result ----
#pragma unroll
            for (int i = 0; i < 3; ++i)
#pragma unroll
                for (int j = 0; j < 4; ++j) {
                    const float v = accB[i][j];
                    if (e == 0)      k1[i][j] = v;
                    else if (e == 1) k2[i][j] = v;
                    else if (e == 2) k3[i][j] = v;
                    else             ke[i][j] = v;
                }
        } // eval loop

        // ---- RK4 3/8 update + output ----
#pragma unroll
        for (int i = 0; i < 3; ++i) {
            const int gr = blk * RPB + rowg * 3 + i;
#pragma unroll
            for (int j = 0; j < 4; ++j) {
                y[i][j] += h * 0.125f * (k1[i][j] + 3.f * k2[i][j] + 3.f * k3[i][j] + ke[i][j]);
                out[(gr * 50 + (s + 1)) * 128 + colg + 32 * j] = y[i][j];
            }
        }
    }
}

extern "C" void kernel_launch(void* const* d_in, const int* in_sizes, int n_in,
                              void* d_out, int out_size, void* d_ws, size_t ws_size,
                              hipStream_t stream) {
    const float* fp     = (const float*)d_in[0];
    const float* tsteps = (const float*)d_in[1];
    const float* W1     = (const float*)d_in[2];
    const float* b1     = (const float*)d_in[3];
    const float* W2     = (const float*)d_in[4];
    const float* b2     = (const float*)d_in[5];
    float* out          = (float*)d_out;

    ode_rk4_kernel<<<NBLK, 256, 0, stream>>>(fp, tsteps, W1, b1, W2, b2, out);
}

// Round 2
// 1098.820 us; speedup vs baseline: 5.1461x; 5.1461x over previous
//
#include <hip/hip_runtime.h>

// DiffeqSolver: 49 RK4(3/8) steps of y' = W2 @ tanh(W1 @ y + b1) + b2
// 6144 independent rows, dim 128 (123+5 aug), hidden 256.
//
// Round 2: fp16 MFMA with Ootomo-style 3-product split precision.
//   x = x_hi(fp16) + 2^-11 * x_lo'(fp16)   (lo scaled by 2^11 to stay normal)
//   x*w ~= x_hi*w_hi  (main acc)  +  2^-11*(x_hi*w_lo' + x_lo'*w_hi) (corr acc)
//   -> ~2^-21 relative error, fp32-class for this ODE (fp32 gave absmax 0.5).
// 256 blocks x 256 threads (4 waves), 24 rows/block padded to M=32.
// Weights held in REGISTERS as per-wave fp16 hi/lo B-fragments (256 VGPR):
//   phase A: wave w owns hidden cols [64w,64w+64), K=128
//   phase B: wave w owns dim    cols [32w,32w+32), K=256
// Solver state y,k1..k4 in LDS (stride 132). A-fragments via LDS.

typedef _Float16 half8  __attribute__((ext_vector_type(8)));
typedef float    floatx4 __attribute__((ext_vector_type(4)));

#define NBLK 256
#define ROWS 24
#define DIM  128
#define HID  256
#define SD   132          // padded fp32 stride for state arrays
#define LOSCALE 2048.0f
#define LOINV   (1.0f/2048.0f)

__device__ __forceinline__ float fast_tanh(float x) {
    // tanh(x) = 1 - 2/(e^{2x}+1); exp->inf gives 1, exp->0 gives -1. ~1e-7 abs err.
    float e = __expf(2.0f * x);
    return 1.0f - 2.0f * __builtin_amdgcn_rcpf(e + 1.0f);
}

__device__ __forceinline__ void build_octet(
    int e, float hstep, int o,
    const float* sy, const float* k1, const float* k2, const float* k3,
    _Float16* yfh, _Float16* yfl)
{
    const int r    = o >> 4;
    const int d0   = (o & 15) << 3;
    const int base = r * SD + d0;
    float v[8];
#pragma unroll
    for (int j = 0; j < 8; ++j) v[j] = sy[base + j];
    if (e == 1) {
        const float c = hstep * (1.0f / 3.0f);
#pragma unroll
        for (int j = 0; j < 8; ++j) v[j] += c * k1[base + j];
    } else if (e == 2) {
        const float c = hstep * (1.0f / 3.0f);
#pragma unroll
        for (int j = 0; j < 8; ++j) v[j] += hstep * k2[base + j] - c * k1[base + j];
    } else if (e == 3) {
#pragma unroll
        for (int j = 0; j < 8; ++j) v[j] += hstep * (k1[base + j] - k2[base + j] + k3[base + j]);
    }
    // A-fragment slot: tile (mt = r>>4, kt = d0>>5), lane2 = (r&15) + 16*q2, q2=(d0>>3)&3
    const int mt = r >> 4;
    const int m  = r & 15;
    const int kt = d0 >> 5;
    const int q2 = (d0 >> 3) & 3;
    const int slot = (((mt << 2) + kt) * 64 + (m + (q2 << 4))) * 8;
    half8 hi, lo;
#pragma unroll
    for (int j = 0; j < 8; ++j) {
        _Float16 h16 = (_Float16)v[j];
        hi[j] = h16;
        lo[j] = (_Float16)((v[j] - (float)h16) * LOSCALE);
    }
    *(half8*)&yfh[slot] = hi;
    *(half8*)&yfl[slot] = lo;
}

__global__ __launch_bounds__(256, 1)
void ode_mfma_kernel(const float* __restrict__ fp,      // (3,2048,123)
                     const float* __restrict__ tsteps,  // (50)
                     const float* __restrict__ W1,      // (256,128)
                     const float* __restrict__ b1,      // (256)
                     const float* __restrict__ W2,      // (128,256)
                     const float* __restrict__ b2,      // (128)
                     float* __restrict__ out)           // (3,2048,50,128)
{
    __shared__ float st_y[ROWS * SD];
    __shared__ float st_k[4][ROWS * SD];
    __shared__ _Float16 yfh[4096], yfl[4096];   // phase A A-frags (2 mt x 4 kt x 64 x 8)
    __shared__ _Float16 hfh[8192], hfl[8192];   // phase B A-frags (2 mt x 8 kt x 64 x 8)
    __shared__ float ts_l[64];

    const int tid  = threadIdx.x;
    const int wave = tid >> 6;
    const int lane = tid & 63;
    const int n16  = lane & 15;
    const int qq   = lane >> 4;
    const int blk  = blockIdx.x;

    // ---- weight preload into registers (fp16 hi + scaled lo B-fragments) ----
    half8 w1h[4][4], w1l[4][4];   // [nt][kt]  B = W1^T : B[k][n] = W1[n][k]
    half8 w2h[2][8], w2l[2][8];   // [nt][kt]  B = W2^T : B[k][n] = W2[n][k]
    float bias1[4], bias2[2];
#pragma unroll
    for (int nt = 0; nt < 4; ++nt) {
        const int c = wave * 64 + nt * 16 + n16;
        bias1[nt] = b1[c];
#pragma unroll
        for (int kt = 0; kt < 4; ++kt) {
            const float* p = W1 + c * DIM + kt * 32 + qq * 8;
#pragma unroll
            for (int j = 0; j < 8; ++j) {
                float v = p[j];
                _Float16 h16 = (_Float16)v;
                w1h[nt][kt][j] = h16;
                w1l[nt][kt][j] = (_Float16)((v - (float)h16) * LOSCALE);
            }
        }
    }
#pragma unroll
    for (int nt = 0; nt < 2; ++nt) {
        const int c = wave * 32 + nt * 16 + n16;
        bias2[nt] = b2[c];
#pragma unroll
        for (int kt = 0; kt < 8; ++kt) {
            const float* p = W2 + c * HID + kt * 32 + qq * 8;
#pragma unroll
            for (int j = 0; j < 8; ++j) {
                float v = p[j];
                _Float16 h16 = (_Float16)v;
                w2h[nt][kt][j] = h16;
                w2l[nt][kt][j] = (_Float16)((v - (float)h16) * LOSCALE);
            }
        }
    }

    // ---- LDS init ----
    if (tid < 50) ts_l[tid] = tsteps[tid];
    for (int i = tid; i < 4096; i += 256) { yfh[i] = (_Float16)0.f; yfl[i] = (_Float16)0.f; }
    for (int i = tid; i < 8192; i += 256) { hfh[i] = (_Float16)0.f; hfl[i] = (_Float16)0.f; }
    for (int i = tid; i < ROWS * DIM; i += 256) {
        const int r = i >> 7, d = i & 127;
        const int gr = blk * ROWS + r;
        float v = (d < 123) ? fp[gr * 123 + d] : 0.f;
        st_y[r * SD + d] = v;
        out[((size_t)(gr * 50 + 0)) * DIM + d] = v;
    }
    __syncthreads();

    for (int s = 0; s < 49; ++s) {
        const float hstep = ts_l[s + 1] - ts_l[s];

        for (int e = 0; e < 4; ++e) {
            // ---- build eval point -> yfrag (row-spread octet mapping) ----
            {
                const int o1 = ((tid & 15) << 4) | (tid >> 4);            // rows 0..15
                build_octet(e, hstep, o1, st_y, st_k[0], st_k[1], st_k[2], yfh, yfl);
                if (tid < 128) {
                    const int o2 = 256 + ((tid & 7) << 4) + (tid >> 3);    // rows 16..23
                    build_octet(e, hstep, o2, st_y, st_k[0], st_k[1], st_k[2], yfh, yfl);
                }
            }
            __syncthreads();

            // ---- phase A: acc(32x64 per wave) = Y @ W1^T + b1 ----
            floatx4 aM[2][4], aC[2][4];
#pragma unroll
            for (int mt = 0; mt < 2; ++mt)
#pragma unroll
                for (int nt = 0; nt < 4; ++nt) {
                    const float b = bias1[nt];
                    aM[mt][nt] = (floatx4){b, b, b, b};
                    aC[mt][nt] = (floatx4){0.f, 0.f, 0.f, 0.f};
                }
#pragma unroll
            for (int kt = 0; kt < 4; ++kt) {
                half8 ah[2], al[2];
#pragma unroll
                for (int mt = 0; mt < 2; ++mt) {
                    const int slot = (((mt << 2) + kt) * 64 + lane) * 8;
                    ah[mt] = *(const half8*)&yfh[slot];
                    al[mt] = *(const half8*)&yfl[slot];
                }
#pragma unroll
                for (int nt = 0; nt < 4; ++nt)
#pragma unroll
                    for (int mt = 0; mt < 2; ++mt) {
                        aM[mt][nt] = __builtin_amdgcn_mfma_f32_16x16x32_f16(ah[mt], w1h[nt][kt], aM[mt][nt], 0, 0, 0);
                        aC[mt][nt] = __builtin_amdgcn_mfma_f32_16x16x32_f16(ah[mt], w1l[nt][kt], aC[mt][nt], 0, 0, 0);
                        aC[mt][nt] = __builtin_amdgcn_mfma_f32_16x16x32_f16(al[mt], w1h[nt][kt], aC[mt][nt], 0, 0, 0);
                    }
            }

            // ---- tanh + split -> hfrag ----
#pragma unroll
            for (int mt = 0; mt < 2; ++mt)
#pragma unroll
                for (int nt = 0; nt < 4; ++nt) {
                    const int hcol = wave * 64 + nt * 16 + n16;
                    const int kt2  = hcol >> 5;
                    const int q2   = (hcol >> 3) & 3;
                    const int j2   = hcol & 7;
#pragma unroll
                    for (int reg = 0; reg < 4; ++reg) {
                        const int r = mt * 16 + qq * 4 + reg;
                        float a = aM[mt][nt][reg] + LOINV * aC[mt][nt][reg];
                        float t = fast_tanh(a);
                        _Float16 th = (_Float16)t;
                        _Float16 tl = (_Float16)((t - (float)th) * LOSCALE);
                        const int mt2   = r >> 4;
                        const int lane2 = (r & 15) + 16 * q2;
                        const int addr  = (((mt2 << 3) + kt2) * 64 + lane2) * 8 + j2;
                        hfh[addr] = th;
                        hfl[addr] = tl;
                    }
                }
            __syncthreads();

            // ---- phase B: acc(32x32 per wave) = H @ W2^T + b2 ----
            floatx4 bM[2][2], bC[2][2];
#pragma unroll
            for (int mt = 0; mt < 2; ++mt)
#pragma unroll
                for (int nt = 0; nt < 2; ++nt) {
                    const float b = bias2[nt];
                    bM[mt][nt] = (floatx4){b, b, b, b};
                    bC[mt][nt] = (floatx4){0.f, 0.f, 0.f, 0.f};
                }
#pragma unroll
            for (int kt = 0; kt < 8; ++kt) {
                half8 ah[2], al[2];
#pragma unroll
                for (int mt = 0; mt < 2; ++mt) {
                    const int slot = (((mt << 3) + kt) * 64 + lane) * 8;
                    ah[mt] = *(const half8*)&hfh[slot];
                    al[mt] = *(const half8*)&hfl[slot];
                }
#pragma unroll
                for (int nt = 0; nt < 2; ++nt)
#pragma unroll
                    for (int mt = 0; mt < 2; ++mt) {
                        bM[mt][nt] = __builtin_amdgcn_mfma_f32_16x16x32_f16(ah[mt], w2h[nt][kt], bM[mt][nt], 0, 0, 0);
                        bC[mt][nt] = __builtin_amdgcn_mfma_f32_16x16x32_f16(ah[mt], w2l[nt][kt], bC[mt][nt], 0, 0, 0);
                        bC[mt][nt] = __builtin_amdgcn_mfma_f32_16x16x32_f16(al[mt], w2h[nt][kt], bC[mt][nt], 0, 0, 0);
                    }
            }

            // ---- write k_e ----
            {
                float* ke = st_k[e];
#pragma unroll
                for (int mt = 0; mt < 2; ++mt)
#pragma unroll
                    for (int nt = 0; nt < 2; ++nt) {
                        const int dcol = wave * 32 + nt * 16 + n16;
#pragma unroll
                        for (int reg = 0; reg < 4; ++reg) {
                            const int r = mt * 16 + qq * 4 + reg;
                            if (r < ROWS)
                                ke[r * SD + dcol] = bM[mt][nt][reg] + LOINV * bC[mt][nt][reg];
                        }
                    }
            }
            __syncthreads();
        } // eval loop

        // ---- RK4 3/8 update + output (linear octet map: coalesced stores) ----
        {
            const float c8 = hstep * 0.125f;
#pragma unroll 1
            for (int o = tid; o < 384; o += 256) {
                const int r    = o >> 4;
                const int d0   = (o & 15) << 3;
                const int base = r * SD + d0;
                float v[8];
#pragma unroll
                for (int j = 0; j < 8; ++j) {
                    const float kk = st_k[0][base + j] + 3.0f * st_k[1][base + j]
                                   + 3.0f * st_k[2][base + j] + st_k[3][base + j];
                    const float ny = st_y[base + j] + c8 * kk;
                    st_y[base + j] = ny;
                    v[j] = ny;
                }
                const int gr = blk * ROWS + r;
                float* po = out + ((size_t)(gr * 50 + s + 1)) * DIM + d0;
                *(floatx4*)&po[0] = (floatx4){v[0], v[1], v[2], v[3]};
                *(floatx4*)&po[4] = (floatx4){v[4], v[5], v[6], v[7]};
            }
        }
        __syncthreads();
    }
}

extern "C" void kernel_launch(void* const* d_in, const int* in_sizes, int n_in,
                              void* d_out, int out_size, void* d_ws, size_t ws_size,
                              hipStream_t stream) {
    const float* fp     = (const float*)d_in[0];
    const float* tsteps = (const float*)d_in[1];
    const float* W1     = (const float*)d_in[2];
    const float* b1     = (const float*)d_in[3];
    const float* W2     = (const float*)d_in[4];
    const float* b2     = (const float*)d_in[5];
    float* out          = (float*)d_out;

    ode_mfma_kernel<<<NBLK, 256, 0, stream>>>(fp, tsteps, W1, b1, W2, b2, out);
}

// Round 4
// 719.072 us; speedup vs baseline: 7.8638x; 1.5281x over previous
//
#include <hip/hip_runtime.h>

// DiffeqSolver: 49 RK4(3/8) steps of y' = W2 @ tanh(W1 @ y + b1) + b2
// 6144 rows, dim 128 (123+5 aug), hidden 256. Output (3,2048,50,128) fp32.
//
// Round 3b: transposed MFMA formulation + 2 waves/SIMD. (3a failed compile:
// reference-to-vector-element; split16 now returns by value.)
//  - Compute H^T = tanh(W1 . Y^T + b1), K^T = W2 . H^T + b2: weights are the
//    A operand (static, in registers), state is the B operand. A/B fragment
//    layouts are symmetric, so frags are the same [row][k-contig] structures;
//    the win: phase-A C-layout lane-col == batch-row == phase-B B-frag lane
//    row, so H publish is per-lane b64 of 4 consecutive h (2-way banks, free)
//    instead of an 8-way-conflicted b16 scatter.
//  - 256 blocks x 512 threads (8 waves, 2/SIMD). Wave w: phase A owns
//    h-tiles {2w,2w+1} x 2 col-tiles (W1 frags 64 VGPR); phase B owns
//    d-tile w x 2 col-tiles (W2 frags 64 VGPR). Total regs ~230 -> 2 waves/EU.
//  - Split precision (validated R2): x = hi(fp16) + 2^-11 * lo'(fp16),
//    3 MFMA products, separate correction accumulator.

typedef _Float16 half8  __attribute__((ext_vector_type(8)));
typedef _Float16 half4  __attribute__((ext_vector_type(4)));
typedef float    floatx4 __attribute__((ext_vector_type(4)));

#define NBLK 256
#define ROWS 24
#define DIM  128
#define HID  256
#define DW   132      // fp32 state row stride (words):  132 mod 32 = 4 -> 2-way
#define YH   136      // yfrag row stride (halfwords):   68 words, mod 32 = 4
#define HH   264      // hfrag row stride (halfwords):  132 words, mod 32 = 4
#define LOSCALE 2048.0f
#define LOINV   (1.0f/2048.0f)

__device__ __forceinline__ float fast_tanh(float x) {
    float e = __expf(2.0f * x);
    return 1.0f - 2.0f * __builtin_amdgcn_rcpf(e + 1.0f);
}

struct h2 { _Float16 hi, lo; };
__device__ __forceinline__ h2 split16(float v) {
    h2 r;
    r.hi = (_Float16)v;
    r.lo = (_Float16)((v - (float)r.hi) * LOSCALE);
    return r;
}

__global__ __launch_bounds__(512, 2)
void ode_mfma_kernel(const float* __restrict__ fp,      // (3,2048,123)
                     const float* __restrict__ tsteps,  // (50)
                     const float* __restrict__ W1,      // (256,128)
                     const float* __restrict__ b1,      // (256)
                     const float* __restrict__ W2,      // (128,256)
                     const float* __restrict__ b2,      // (128)
                     float* __restrict__ out)           // (3,2048,50,128)
{
    __shared__ float st_y[ROWS * DW];
    __shared__ float st_k[4][ROWS * DW];
    __shared__ __align__(16) _Float16 yfh[32 * YH], yfl[32 * YH];  // Y^T B-frags
    __shared__ __align__(16) _Float16 hfh[32 * HH], hfl[32 * HH];  // H^T B-frags
    __shared__ float ts_l[64];

    const int tid  = threadIdx.x;
    const int wave = tid >> 6;
    const int lane = tid & 63;
    const int n16  = lane & 15;
    const int quad = lane >> 4;
    const int blk  = blockIdx.x;

    // ---- static weight fragments (A-operand layout: m=lane&15, k=quad*8+j) ----
    half8 w1h[2][4], w1l[2][4];      // [i (ht=2w+i)][kt]
    half8 w2h[8],    w2l[8];         // [kt], dt = wave
    floatx4 bias1[2], bias2;
#pragma unroll
    for (int i = 0; i < 2; ++i) {
        const int h = 32 * wave + 16 * i + n16;
        bias1[i] = *(const floatx4*)(b1 + 32 * wave + 16 * i + 4 * quad);
#pragma unroll
        for (int kt = 0; kt < 4; ++kt) {
            const float* p = W1 + h * DIM + kt * 32 + quad * 8;
#pragma unroll
            for (int j = 0; j < 8; ++j) {
                h2 sp = split16(p[j]);
                w1h[i][kt][j] = sp.hi;
                w1l[i][kt][j] = sp.lo;
            }
        }
    }
    {
        const int d = 16 * wave + n16;
        bias2 = *(const floatx4*)(b2 + 16 * wave + 4 * quad);
#pragma unroll
        for (int kt = 0; kt < 8; ++kt) {
            const float* p = W2 + d * HID + kt * 32 + quad * 8;
#pragma unroll
            for (int j = 0; j < 8; ++j) {
                h2 sp = split16(p[j]);
                w2h[kt][j] = sp.hi;
                w2l[kt][j] = sp.lo;
            }
        }
    }

    // ---- init: ts, pad rows of yfrag, initial state + t=0 output ----
    if (tid < 50) ts_l[tid] = tsteps[tid];
    for (int i = tid; i < 8 * YH; i += 512) {
        yfh[24 * YH + i] = (_Float16)0.f;
        yfl[24 * YH + i] = (_Float16)0.f;
    }
    if (tid < 384) {
        const int r = tid >> 4, c = tid & 15;
        const int gr = blk * ROWS + r;
        float v[8];
#pragma unroll
        for (int j = 0; j < 8; ++j) {
            const int d = c * 8 + j;
            v[j] = (d < 123) ? fp[gr * 123 + d] : 0.f;
            st_y[r * DW + c * 8 + j] = v[j];
        }
        float* po = out + ((size_t)gr * 50) * DIM + c * 8;
        *(floatx4*)&po[0] = (floatx4){v[0], v[1], v[2], v[3]};
        *(floatx4*)&po[4] = (floatx4){v[4], v[5], v[6], v[7]};
    }
    __syncthreads();

    for (int s = 0; s < 49; ++s) {
        const float hstep = ts_l[s + 1] - ts_l[s];

        for (int e = 0; e < 4; ++e) {
            // ---- build eval point -> Y^T B-frags (map: r=tid&31, c=tid>>5) ----
            {
                const int br = tid & 31, bc = tid >> 5;
                if (br < 24) {
                    const int base = br * DW + bc * 8;
                    float v[8];
                    *(floatx4*)&v[0] = *(const floatx4*)&st_y[base];
                    *(floatx4*)&v[4] = *(const floatx4*)&st_y[base + 4];
                    if (e == 1) {
                        const float c3 = hstep * (1.0f / 3.0f);
#pragma unroll
                        for (int j = 0; j < 8; ++j) v[j] += c3 * st_k[0][base + j];
                    } else if (e == 2) {
                        const float c3 = hstep * (1.0f / 3.0f);
#pragma unroll
                        for (int j = 0; j < 8; ++j)
                            v[j] += hstep * st_k[1][base + j] - c3 * st_k[0][base + j];
                    } else if (e == 3) {
#pragma unroll
                        for (int j = 0; j < 8; ++j)
                            v[j] += hstep * (st_k[0][base + j] - st_k[1][base + j] + st_k[2][base + j]);
                    }
                    half8 hi, lo;
#pragma unroll
                    for (int j = 0; j < 8; ++j) {
                        h2 sp = split16(v[j]);
                        hi[j] = sp.hi;
                        lo[j] = sp.lo;
                    }
                    *(half8*)&yfh[br * YH + bc * 8] = hi;
                    *(half8*)&yfl[br * YH + bc * 8] = lo;
                }
            }
            __syncthreads();

            // ---- phase A: H^T tiles = W1 . Y^T + b1 ----
            floatx4 aM[2][2], aC[2][2];   // [i][ct]
#pragma unroll
            for (int i = 0; i < 2; ++i)
#pragma unroll
                for (int ct = 0; ct < 2; ++ct) {
                    aM[i][ct] = bias1[i];
                    aC[i][ct] = (floatx4){0.f, 0.f, 0.f, 0.f};
                }
#pragma unroll
            for (int kt = 0; kt < 4; ++kt) {
                half8 ybh[2], ybl[2];
#pragma unroll
                for (int ct = 0; ct < 2; ++ct) {
                    const int a = (16 * ct + n16) * YH + kt * 32 + quad * 8;
                    ybh[ct] = *(const half8*)&yfh[a];
                    ybl[ct] = *(const half8*)&yfl[a];
                }
#pragma unroll
                for (int i = 0; i < 2; ++i)
#pragma unroll
                    for (int ct = 0; ct < 2; ++ct) {
                        aM[i][ct] = __builtin_amdgcn_mfma_f32_16x16x32_f16(w1h[i][kt], ybh[ct], aM[i][ct], 0, 0, 0);
                        aC[i][ct] = __builtin_amdgcn_mfma_f32_16x16x32_f16(w1l[i][kt], ybh[ct], aC[i][ct], 0, 0, 0);
                        aC[i][ct] = __builtin_amdgcn_mfma_f32_16x16x32_f16(w1h[i][kt], ybl[ct], aC[i][ct], 0, 0, 0);
                    }
            }

            // ---- tanh + publish H^T B-frags (per-lane b64, 4 consecutive h) ----
#pragma unroll
            for (int i = 0; i < 2; ++i)
#pragma unroll
                for (int ct = 0; ct < 2; ++ct) {
                    const int r  = 16 * ct + n16;
                    const int h0 = 32 * wave + 16 * i + 4 * quad;
                    half4 th, tl;
#pragma unroll
                    for (int reg = 0; reg < 4; ++reg) {
                        const float a = aM[i][ct][reg] + LOINV * aC[i][ct][reg];
                        const float t = fast_tanh(a);
                        h2 sp = split16(t);
                        th[reg] = sp.hi;
                        tl[reg] = sp.lo;
                    }
                    *(half4*)&hfh[r * HH + h0] = th;
                    *(half4*)&hfl[r * HH + h0] = tl;
                }
            __syncthreads();

            // ---- phase B: K^T tiles = W2 . H^T + b2 ----
            floatx4 bM[2], bC[2];
#pragma unroll
            for (int ct = 0; ct < 2; ++ct) {
                bM[ct] = bias2;
                bC[ct] = (floatx4){0.f, 0.f, 0.f, 0.f};
            }
#pragma unroll
            for (int kt = 0; kt < 8; ++kt) {
                half8 hbh[2], hbl[2];
#pragma unroll
                for (int ct = 0; ct < 2; ++ct) {
                    const int a = (16 * ct + n16) * HH + kt * 32 + quad * 8;
                    hbh[ct] = *(const half8*)&hfh[a];
                    hbl[ct] = *(const half8*)&hfl[a];
                }
#pragma unroll
                for (int ct = 0; ct < 2; ++ct) {
                    bM[ct] = __builtin_amdgcn_mfma_f32_16x16x32_f16(w2h[kt], hbh[ct], bM[ct], 0, 0, 0);
                    bC[ct] = __builtin_amdgcn_mfma_f32_16x16x32_f16(w2l[kt], hbh[ct], bC[ct], 0, 0, 0);
                    bC[ct] = __builtin_amdgcn_mfma_f32_16x16x32_f16(w2h[kt], hbl[ct], bC[ct], 0, 0, 0);
                }
            }

            // ---- publish k_e (per-lane b128, 4 consecutive d) ----
            {
                float* ke = st_k[e];
#pragma unroll
                for (int ct = 0; ct < 2; ++ct) {
                    const int r = 16 * ct + n16;
                    floatx4 kv;
#pragma unroll
                    for (int reg = 0; reg < 4; ++reg)
                        kv[reg] = bM[ct][reg] + LOINV * bC[ct][reg];
                    if (r < 24)
                        *(floatx4*)&ke[r * DW + 16 * wave + 4 * quad] = kv;
                }
            }
            __syncthreads();
        } // eval loop

        // ---- RK4 3/8 update + output (map r=tid>>4: coalesced global) ----
        if (tid < 384) {
            const float c8 = hstep * 0.125f;
            const int r = tid >> 4, c = tid & 15;
            const int base = r * DW + c * 8;
            float v[8];
#pragma unroll
            for (int j = 0; j < 8; ++j) {
                const float kk = st_k[0][base + j] + 3.0f * st_k[1][base + j]
                               + 3.0f * st_k[2][base + j] + st_k[3][base + j];
                v[j] = st_y[base + j] + c8 * kk;
                st_y[base + j] = v[j];
            }
            const int gr = blk * ROWS + r;
            float* po = out + ((size_t)(gr * 50 + s + 1)) * DIM + c * 8;
            *(floatx4*)&po[0] = (floatx4){v[0], v[1], v[2], v[3]};
            *(floatx4*)&po[4] = (floatx4){v[4], v[5], v[6], v[7]};
        }
        __syncthreads();
    }
}

extern "C" void kernel_launch(void* const* d_in, const int* in_sizes, int n_in,
                              void* d_out, int out_size, void* d_ws, size_t ws_size,
                              hipStream_t stream) {
    const float* fp     = (const float*)d_in[0];
    const float* tsteps = (const float*)d_in[1];
    const float* W1     = (const float*)d_in[2];
    const float* b1     = (const float*)d_in[3];
    const float* W2     = (const float*)d_in[4];
    const float* b2     = (const float*)d_in[5];
    float* out          = (float*)d_out;

    ode_mfma_kernel<<<NBLK, 512, 0, stream>>>(fp, tsteps, W1, b1, W2, b2, out);
}